// Round 9
// baseline (186.056 us; speedup 1.0000x reference)
//
#include <hip/hip_runtime.h>
#include <hip/hip_bf16.h>
#include <math.h>

#define NRES 512
#define CS   384
#define CZ   128
#define NH   12
#define PW   1152   // packed projection width
#define JB   64     // j per flash block
#define NCH  8      // chunks = NRES/JB
#define PSTRIDE32 1040  // part chunk stride in u32 units
#define KSPLIT 11   // k_out K splits (2112 = 11*192)
#define KAW  352    // Kfull row width (11 * 32)

static constexpr float WL_F      = 0.57735026918962576f;   // sqrt(1/3)
static constexpr float HALF_WC_F = 0.11785113019775792f;   // 0.5*sqrt(2/(9*4))

typedef __attribute__((ext_vector_type(8))) short short8v;
typedef __attribute__((ext_vector_type(4))) float floatx4;

__device__ __forceinline__ ushort f2b(float f) {
    union { float f; uint u; } v; v.f = f;
    return (ushort)((v.u + 0x7FFFu + ((v.u >> 16) & 1u)) >> 16);
}
__device__ __forceinline__ float b2f(ushort b) {
    union { uint u; float f; } v; v.u = ((uint)b) << 16; return v.f;
}

// ---------------------------------------------------------------------------
// Kernel 0: pack Wcat[384][1152]; block 0 packs WbT16[16][128] bf16 scaled
// by W_L (rows >= 12 zero).
// ---------------------------------------------------------------------------
__global__ __launch_bounds__(256) void k_pack(
    const float* __restrict__ Wq, const float* __restrict__ Wk,
    const float* __restrict__ Wv, const float* __restrict__ Wqp,
    const float* __restrict__ Wkp, const float* __restrict__ Wvp,
    const float* __restrict__ Wb,
    float* __restrict__ Wcat, ushort* __restrict__ wbt16)
{
    const int c = blockIdx.x;
    for (int col = threadIdx.x; col < PW; col += 256) {
        float v;
        if (col < 192)      v = Wq [(size_t)c * 192 + col];
        else if (col < 384) v = Wk [(size_t)c * 192 + col - 192];
        else if (col < 576) v = Wv [(size_t)c * 192 + col - 384];
        else if (col < 720) v = Wqp[(size_t)c * 144 + col - 576];
        else if (col < 864) v = Wkp[(size_t)c * 144 + col - 720];
        else                v = Wvp[(size_t)c * 288 + col - 864];
        Wcat[(size_t)c * PW + col] = v;
    }
    if (blockIdx.x == 0) {
        for (int idx = threadIdx.x; idx < 16 * 128; idx += 256) {
            const int h = idx >> 7, cc = idx & 127;
            wbt16[idx] = (h < NH) ? f2b(WL_F * Wb[(size_t)cc * NH + h]) : (ushort)0;
        }
    }
}

// ---------------------------------------------------------------------------
// Kernel 1: P[512][1152] = s @ Wcat, rigid transform fused for cols >= 576.
// ---------------------------------------------------------------------------
__global__ __launch_bounds__(256) void k_gemm(
    const float* __restrict__ s, const float* __restrict__ Wcat,
    const float* __restrict__ rots, const float* __restrict__ trans,
    float* __restrict__ P)
{
    const int tid = threadIdx.x;
    const int tx = tid & 15, ty = tid >> 4;
    const int n0 = blockIdx.x * 48;
    const int m0 = blockIdx.y * 32;
    __shared__ float As[32][34];
    __shared__ float Bs[32][50];
    __shared__ float rot_lds[32][12];

    if (n0 >= 576) {
        for (int idx = tid; idx < 32 * 12; idx += 256) {
            int r = idx / 12, q = idx % 12;
            rot_lds[r][q] = (q < 9) ? rots[(size_t)(m0 + r) * 9 + q]
                                    : trans[(size_t)(m0 + r) * 3 + q - 9];
        }
    }

    float acc[2][3];
    #pragma unroll
    for (int u = 0; u < 2; ++u)
        #pragma unroll
        for (int v = 0; v < 3; ++v) acc[u][v] = 0.f;

    for (int k0 = 0; k0 < CS; k0 += 32) {
        __syncthreads();
        #pragma unroll
        for (int l = 0; l < 4; ++l) {
            int idx = tid + l * 256;
            int kk = idx & 31, r = idx >> 5;
            As[kk][r] = s[(size_t)(m0 + r) * CS + k0 + kk];
        }
        #pragma unroll
        for (int l = 0; l < 6; ++l) {
            int idx = tid + l * 256;
            int kk = idx / 48, cc = idx % 48;
            Bs[kk][cc] = Wcat[(size_t)(k0 + kk) * PW + n0 + cc];
        }
        __syncthreads();
        #pragma unroll
        for (int kk = 0; kk < 32; ++kk) {
            const float2 a = *(const float2*)&As[kk][ty * 2];
            const float b0 = Bs[kk][tx * 3], b1 = Bs[kk][tx * 3 + 1], b2 = Bs[kk][tx * 3 + 2];
            acc[0][0] += a.x * b0; acc[0][1] += a.x * b1; acc[0][2] += a.x * b2;
            acc[1][0] += a.y * b0; acc[1][1] += a.y * b1; acc[1][2] += a.y * b2;
        }
    }

    #pragma unroll
    for (int u = 0; u < 2; ++u) {
        float v0 = acc[u][0], v1 = acc[u][1], v2 = acc[u][2];
        if (n0 >= 576) {
            const float* RT = rot_lds[ty * 2 + u];
            const float p0 = v0, p1 = v1, p2 = v2;
            v0 = RT[0] * p0 + RT[1] * p1 + RT[2] * p2 + RT[9];
            v1 = RT[3] * p0 + RT[4] * p1 + RT[5] * p2 + RT[10];
            v2 = RT[6] * p0 + RT[7] * p1 + RT[8] * p2 + RT[11];
        }
        float* dst = P + (size_t)(m0 + ty * 2 + u) * PW + n0 + tx * 3;
        dst[0] = v0; dst[1] = v1; dst[2] = v2;
    }
}

// ---------------------------------------------------------------------------
// Kernel 1b: Kfull[512][352] bf16 augmented K rows:
// [0,192) k | [192,336) kg | [336,348) nj_h | 348: 1 | pad
// Also emits VT[480][512] bf16: rows [0,192)=vh^T, [192,480)=vg^T.
// ---------------------------------------------------------------------------
__global__ __launch_bounds__(128) void k_ka(
    const float* __restrict__ P, ushort* __restrict__ Kfull,
    ushort* __restrict__ VT)
{
    const int j = blockIdx.x;
    const int tid = threadIdx.x;
    __shared__ float njs[NH];
    const float* kr  = P + (size_t)j * PW + 192;
    const float* kgr = P + (size_t)j * PW + 720;
    const float* vr  = P + (size_t)j * PW + 384;
    const float* vgr = P + (size_t)j * PW + 864;
    if (tid < NH) {
        float s = 0.f;
        #pragma unroll
        for (int e = 0; e < 12; ++e) { const float v = kgr[tid * 12 + e]; s += v * v; }
        njs[tid] = s;
    }
    __syncthreads();
    ushort* dst = Kfull + (size_t)j * KAW;
    for (int t = tid; t < KAW; t += 128) {
        float v;
        if (t < 192)       v = kr[t];
        else if (t < 336)  v = kgr[t - 192];
        else if (t < 348)  v = njs[t - 336];
        else if (t == 348) v = 1.0f;
        else               v = 0.f;
        dst[t] = f2b(v);
    }
    for (int t = tid; t < 480; t += 128) {
        const float v = (t < 192) ? vr[t] : vgr[t - 192];
        VT[(size_t)t * NRES + j] = f2b(v);
    }
}

// ---------------------------------------------------------------------------
// Kernel 2: MFMA flash chunk. grid (512 i, 8 jc), 256 threads (4 waves).
// Logits = one fused MFMA chain (15 steps); softmax; then per wave:
// 2 o_hat N-tiles (B from zbT LDS) + 8 V-tiles (B from global VT) — o and
// o_hp fully on the MFMA pipe, no vector j-loop, no reduce barrier.
// part chunk (u32 stride 1040): u16[0,1536) ohat | [1536,1728) o |
// [1728,2016) ohp ; f32 @u32 1008+h = pm, 1020+h = ps.
// ---------------------------------------------------------------------------
__global__ __launch_bounds__(256) void k_flash(
    const float* __restrict__ z, const ushort* __restrict__ wbt16,
    const float* __restrict__ gamma, const float* __restrict__ P,
    const ushort* __restrict__ Kfull, const ushort* __restrict__ VT,
    uint* __restrict__ part)
{
    const int i   = blockIdx.x;
    const int jc  = blockIdx.y;
    const int j0  = jc * JB;
    const int tid = threadIdx.x;
    const int wid = tid >> 6, lane = tid & 63;

    __shared__ __align__(16) short zbT[128 * JB];    // 16 KB
    __shared__ __align__(16) short BfT[16 * 488];    // 15.6 KB, B^T [n=16][k=488]
    __shared__ __align__(16) short ltb[16 * 64];     // 2 KB
    __shared__ float ltf[16 * 68];                   // 4.35 KB
    __shared__ float pm[NH], ps[NH];

    uint* pb32   = part + ((size_t)i * NCH + jc) * PSTRIDE32;
    ushort* pb16 = (ushort*)pb32;
    float* pbf   = (float*)pb32;

    // ---- phase 1: zero BfT ----
    for (int idx = tid; idx < 16 * 488 / 2; idx += 256) ((uint*)BfT)[idx] = 0u;
    __syncthreads();

    // ---- phase 2: zbT staging + BfT scatter ----
    {
        const float4* zr = (const float4*)(z + ((size_t)i * NRES + j0 + lane) * CZ + wid * 32);
        float f[32];
        #pragma unroll
        for (int k = 0; k < 8; ++k) {
            const float4 t = zr[k];
            f[k * 4 + 0] = t.x; f[k * 4 + 1] = t.y;
            f[k * 4 + 2] = t.z; f[k * 4 + 3] = t.w;
        }
        #pragma unroll
        for (int m = 0; m < 32; ++m) {
            const int c = wid * 32 + m;
            zbT[c * 64 + (((lane >> 3) ^ (c & 7)) * 8) + (lane & 7)] = (short)f2b(f[m]);
        }
    }
    {
        const float* prow = P + (size_t)i * PW;
        for (int t = tid; t < 360; t += 256) {
            if (t < 192) {
                const int h = t >> 4;
                BfT[h * 488 + t] = (short)f2b(0.25f * WL_F * prow[t]);
            } else if (t < 336) {
                const int e = t - 192, h = e / 12;
                BfT[h * 488 + t] =
                    (short)f2b(2.f * HALF_WC_F * WL_F * gamma[h] * prow[576 + e]);
            } else if (t < 348) {
                const int h = t - 336;
                BfT[h * 488 + t] = (short)f2b(-HALF_WC_F * WL_F * gamma[h]);
            } else {
                const int h = t - 348;
                float s = 0.f;
                #pragma unroll
                for (int e = 0; e < 12; ++e) {
                    const float v = prow[576 + h * 12 + e];
                    s += v * v;
                }
                BfT[h * 488 + 348] = (short)f2b(-HALF_WC_F * WL_F * gamma[h] * s);
            }
        }
        for (int idx = tid; idx < 1024; idx += 256) {
            const int h = idx >> 6, c2 = idx & 63;
            *(uint*)&BfT[h * 488 + 352 + c2 * 2] = ((const uint*)wbt16)[h * 64 + c2];
        }
    }
    __syncthreads();

    // ---- phase 3: fused logits MFMA (15 K-steps) ----
    {
        const int jb = wid * 16 + (lane & 15);
        const int n  = lane & 15;
        const int ko = (lane >> 4) * 8;
        const ushort* arow = Kfull + (size_t)(j0 + jb) * KAW + ko;
        const short*  brow = &BfT[n * 488 + ko];
        const float*  za   = z + ((size_t)i * NRES + j0 + jb) * CZ + ko;
        floatx4 acc = {0.f, 0.f, 0.f, 0.f};
        #pragma unroll
        for (int st = 0; st < 11; ++st) {
            const short8v a = *(const short8v*)(arow + st * 32);
            const short8v b = *(const short8v*)(brow + st * 32);
            acc = __builtin_amdgcn_mfma_f32_16x16x32_bf16(a, b, acc, 0, 0, 0);
        }
        #pragma unroll
        for (int st = 0; st < 4; ++st) {
            const float4 f0 = *(const float4*)(za + st * 32);
            const float4 f1 = *(const float4*)(za + st * 32 + 4);
            short8v a;
            a[0] = (short)f2b(f0.x); a[1] = (short)f2b(f0.y);
            a[2] = (short)f2b(f0.z); a[3] = (short)f2b(f0.w);
            a[4] = (short)f2b(f1.x); a[5] = (short)f2b(f1.y);
            a[6] = (short)f2b(f1.z); a[7] = (short)f2b(f1.w);
            const short8v b = *(const short8v*)(brow + (11 + st) * 32);
            acc = __builtin_amdgcn_mfma_f32_16x16x32_bf16(a, b, acc, 0, 0, 0);
        }
        #pragma unroll
        for (int r = 0; r < 4; ++r)
            ltf[n * 68 + wid * 16 + (lane >> 4) * 4 + r] = acc[r];
    }
    __syncthreads();

    // ---- phase 4: chunk softmax (16 lanes/head) + bf16 prob write ----
    if (tid < 192) {
        const int h = tid >> 4, s = tid & 15;
        float4 v = *(const float4*)&ltf[h * 68 + s * 4];
        float m = fmaxf(fmaxf(v.x, v.y), fmaxf(v.z, v.w));
        #pragma unroll
        for (int o = 1; o < 16; o <<= 1) m = fmaxf(m, __shfl_xor(m, o));
        float4 e;
        e.x = __expf(v.x - m); e.y = __expf(v.y - m);
        e.z = __expf(v.z - m); e.w = __expf(v.w - m);
        float sum = e.x + e.y + e.z + e.w;
        #pragma unroll
        for (int o = 1; o < 16; o <<= 1) sum += __shfl_xor(sum, o);
        const uint lo = (uint)f2b(e.x) | ((uint)f2b(e.y) << 16);
        const uint hi = (uint)f2b(e.z) | ((uint)f2b(e.w) << 16);
        uint* dst = (uint*)&ltb[h * 64 + (((s >> 1) ^ (h & 7)) * 8) + (s & 1) * 4];
        dst[0] = lo; dst[1] = hi;
        if (s == 0) { pm[h] = m; ps[h] = sum; }
    } else {
        const int tt = tid - 192;
        uint* dst = (uint*)&ltb[(12 + (tt >> 4)) * 64 + (tt & 15) * 4];
        dst[0] = 0u; dst[1] = 0u;
    }
    __syncthreads();

    // ---- phase 5: o_hat (2 N-tiles) + o/o_hp (8 V-tiles) MFMA per wave ----
    {
        const int hrow = lane & 15;
        const int u0 = (lane >> 4), u1 = u0 + 4;
        const short8v a0 = *(const short8v*)&ltb[hrow * 64 + ((u0 ^ (hrow & 7)) * 8)];
        const short8v a1 = *(const short8v*)&ltb[hrow * 64 + ((u1 ^ (hrow & 7)) * 8)];

        #pragma unroll
        for (int t = 0; t < 2; ++t) {
            const int d = (wid * 2 + t) * 16 + (lane & 15);
            const short8v b0 = *(const short8v*)&zbT[d * 64 + ((u0 ^ (d & 7)) * 8)];
            const short8v b1 = *(const short8v*)&zbT[d * 64 + ((u1 ^ (d & 7)) * 8)];
            floatx4 acc = {0.f, 0.f, 0.f, 0.f};
            acc = __builtin_amdgcn_mfma_f32_16x16x32_bf16(a0, b0, acc, 0, 0, 0);
            acc = __builtin_amdgcn_mfma_f32_16x16x32_bf16(a1, b1, acc, 0, 0, 0);
            #pragma unroll
            for (int r = 0; r < 4; ++r) {
                const int h = u0 * 4 + r;
                if (h < NH) pb16[h * 128 + d] = f2b(acc[r]);
            }
        }

        #pragma unroll
        for (int tl = 0; tl < 8; ++tl) {
            const int tile = wid * 8 + tl;
            if (tile < 30) {
                const int vcol = tile * 16 + (lane & 15);       // [0,480)
                const ushort* vrow = VT + (size_t)vcol * NRES + j0 + u0 * 8;
                const short8v b0 = *(const short8v*)(vrow);
                const short8v b1 = *(const short8v*)(vrow + 32);
                floatx4 acc = {0.f, 0.f, 0.f, 0.f};
                acc = __builtin_amdgcn_mfma_f32_16x16x32_bf16(a0, b0, acc, 0, 0, 0);
                acc = __builtin_amdgcn_mfma_f32_16x16x32_bf16(a1, b1, acc, 0, 0, 0);
                #pragma unroll
                for (int r = 0; r < 4; ++r) {
                    const int h = u0 * 4 + r;
                    if (tile < 12) {
                        if (h == tile) pb16[1536 + vcol] = f2b(acc[r]);
                    } else {
                        const int cc = vcol - 192;               // [0,288)
                        if (h == cc / 24) pb16[1728 + cc] = f2b(acc[r]);
                    }
                }
            }
        }
        if (tid < NH) { pbf[1008 + tid] = pm[tid]; pbf[1020 + tid] = ps[tid]; }
    }
}

// ---------------------------------------------------------------------------
// Kernel 3: combine 8 chunks -> cat row. grid 512, 256 threads.
// ---------------------------------------------------------------------------
__global__ __launch_bounds__(256) void k_combine(
    const uint* __restrict__ part, const float* __restrict__ rots,
    const float* __restrict__ trans, float* __restrict__ cat)
{
    const int i   = blockIdx.x;
    const int tid = threadIdx.x;
    __shared__ float wgt[NCH][NH];
    __shared__ float ohp[288];

    const uint* base = part + (size_t)i * NCH * PSTRIDE32;
    if (tid < NH) {
        const int h = tid;
        float mm[NCH];
        float M = -1e30f;
        #pragma unroll
        for (int c = 0; c < NCH; ++c) {
            mm[c] = ((const float*)(base + c * PSTRIDE32))[1008 + h];
            M = fmaxf(M, mm[c]);
        }
        float S = 0.f;
        #pragma unroll
        for (int c = 0; c < NCH; ++c) {
            const float w = __expf(mm[c] - M);
            S += w * ((const float*)(base + c * PSTRIDE32))[1020 + h];
            wgt[c][h] = w;
        }
        const float inv = 1.0f / S;
        #pragma unroll
        for (int c = 0; c < NCH; ++c) wgt[c][h] *= inv;
    }
    __syncthreads();

    float* crow = cat + (size_t)i * 2112;
    for (int idx2 = tid; idx2 < 768; idx2 += 256) {
        const int h = idx2 >> 6;
        float v0 = 0.f, v1 = 0.f;
        #pragma unroll
        for (int c = 0; c < NCH; ++c) {
            const uint u = base[c * PSTRIDE32 + idx2];
            const float w = wgt[c][h];
            v0 += b2f((ushort)u) * w;
            v1 += b2f((ushort)(u >> 16)) * w;
        }
        *(float2*)&crow[idx2 * 2] = make_float2(v0, v1);
    }
    if (tid < 96) {
        const int h = tid >> 3;
        float v0 = 0.f, v1 = 0.f;
        #pragma unroll
        for (int c = 0; c < NCH; ++c) {
            const uint u = base[c * PSTRIDE32 + 768 + tid];
            const float w = wgt[c][h];
            v0 += b2f((ushort)u) * w;
            v1 += b2f((ushort)(u >> 16)) * w;
        }
        *(float2*)&crow[1536 + tid * 2] = make_float2(v0, v1);
    }
    if (tid < 144) {
        const int h = tid / 12;
        float v0 = 0.f, v1 = 0.f;
        #pragma unroll
        for (int c = 0; c < NCH; ++c) {
            const uint u = base[c * PSTRIDE32 + 864 + tid];
            const float w = wgt[c][h];
            v0 += b2f((ushort)u) * w;
            v1 += b2f((ushort)(u >> 16)) * w;
        }
        ohp[tid * 2] = v0; ohp[tid * 2 + 1] = v1;
    }
    __syncthreads();

    if (tid < 96) {
        const int h = tid >> 3, p = tid & 7;
        float R[9];
        #pragma unroll
        for (int k = 0; k < 9; ++k) R[k] = rots[(size_t)i * 9 + k];
        const float g0 = ohp[h * 24 + p * 3 + 0] - trans[(size_t)i * 3 + 0];
        const float g1 = ohp[h * 24 + p * 3 + 1] - trans[(size_t)i * 3 + 1];
        const float g2 = ohp[h * 24 + p * 3 + 2] - trans[(size_t)i * 3 + 2];
        const float oy0 = R[0] * g0 + R[3] * g1 + R[6] * g2;
        const float oy1 = R[1] * g0 + R[4] * g1 + R[7] * g2;
        const float oy2 = R[2] * g0 + R[5] * g1 + R[8] * g2;
        crow[1728 + h * 24 + p * 3 + 0] = oy0;
        crow[1728 + h * 24 + p * 3 + 1] = oy1;
        crow[1728 + h * 24 + p * 3 + 2] = oy2;
        crow[2016 + h * 8 + p] = sqrtf(oy0 * oy0 + oy1 * oy1 + oy2 * oy2);
    }
}

// ---------------------------------------------------------------------------
// Kernel 4: out-proj partials. grid (3 ctile, 64 rtile, 11 ksplit of 192).
// ---------------------------------------------------------------------------
__global__ __launch_bounds__(256) void k_out(
    const float* __restrict__ cat, const float* __restrict__ Wout,
    float* __restrict__ opart)
{
    const int tid = threadIdx.x;
    const int cp  = tid & 63;
    const int qd  = tid >> 6;
    const int c0  = blockIdx.x * 128 + cp * 2;
    const int i0  = blockIdx.y * 8;
    const int k0  = blockIdx.z * 192;
    const int r0  = qd * 2, r1 = r0 + 1;
    __shared__ float lds[8][65];
    float a00 = 0.f, a01 = 0.f, a10 = 0.f, a11 = 0.f;
    for (int kc = k0; kc < k0 + 192; kc += 64) {
        __syncthreads();
        for (int idx = tid; idx < 512; idx += 256) {
            int r = idx >> 6, kk = idx & 63;
            lds[r][kk] = cat[(size_t)(i0 + r) * 2112 + kc + kk];
        }
        __syncthreads();
        #pragma unroll 8
        for (int kk = 0; kk < 64; ++kk) {
            const float2 w = *(const float2*)(Wout + (size_t)(kc + kk) * 384 + c0);
            float l0 = lds[r0][kk], l1 = lds[r1][kk];
            a00 += l0 * w.x; a01 += l0 * w.y;
            a10 += l1 * w.x; a11 += l1 * w.y;
        }
    }
    float* ob = opart + (size_t)blockIdx.z * 512 * 384;
    ob[(size_t)(i0 + r0) * 384 + c0]     = a00;
    ob[(size_t)(i0 + r0) * 384 + c0 + 1] = a01;
    ob[(size_t)(i0 + r1) * 384 + c0]     = a10;
    ob[(size_t)(i0 + r1) * 384 + c0 + 1] = a11;
}

// Kernel 5: reduce 11 k-partials + bias.
__global__ __launch_bounds__(256) void k_outred(
    const float* __restrict__ opart, const float* __restrict__ bout,
    float* __restrict__ out)
{
    const int e4 = blockIdx.x * 256 + threadIdx.x;
    const float4* p = (const float4*)opart;
    const float4 b = ((const float4*)bout)[e4 % 96];
    float4 r = b;
    #pragma unroll
    for (int k = 0; k < KSPLIT; ++k) {
        const float4 v = p[e4 + k * 49152];
        r.x += v.x; r.y += v.y; r.z += v.z; r.w += v.w;
    }
    ((float4*)out)[e4] = r;
}

// ---------------------------------------------------------------------------
extern "C" void kernel_launch(void* const* d_in, const int* in_sizes, int n_in,
                              void* d_out, int out_size, void* d_ws, size_t ws_size,
                              hipStream_t stream)
{
    const float* s_i   = (const float*)d_in[0];
    const float* z_ij  = (const float*)d_in[1];
    const float* rots  = (const float*)d_in[2];
    const float* trans = (const float*)d_in[3];
    const float* Wq    = (const float*)d_in[4];
    const float* Wk    = (const float*)d_in[5];
    const float* Wv    = (const float*)d_in[6];
    const float* Wqp   = (const float*)d_in[7];
    const float* Wkp   = (const float*)d_in[8];
    const float* Wvp   = (const float*)d_in[9];
    const float* Wb    = (const float*)d_in[10];
    const float* gamma = (const float*)d_in[11];
    const float* Wout  = (const float*)d_in[12];
    const float* bout  = (const float*)d_in[13];
    float* ws = (float*)d_ws;
    float*  wcat  = ws;                          // 442368 f
    float*  P     = ws + 442368;                 // 589824 f
    uint*   part  = (uint*)(P + 589824);         // 512*8*1040 u32
    float*  opart = (float*)part;                // aliased (sequenced)
    float*  cat   = (float*)(part + (size_t)512 * NCH * PSTRIDE32);  // 1081344 f
    ushort* wbt16 = (ushort*)(cat + 1081344);    // 2048 u16
    ushort* kfull = wbt16 + 2048;                // 512*352 u16
    ushort* vt    = kfull + 512 * KAW;           // 480*512 u16
    float*  out   = (float*)d_out;

    hipLaunchKernelGGL(k_pack, dim3(384), dim3(256), 0, stream,
                       Wq, Wk, Wv, Wqp, Wkp, Wvp, Wb, wcat, wbt16);
    hipLaunchKernelGGL(k_gemm, dim3(24, 16), dim3(256), 0, stream,
                       s_i, wcat, rots, trans, P);
    hipLaunchKernelGGL(k_ka, dim3(512), dim3(128), 0, stream, P, kfull, vt);
    hipLaunchKernelGGL(k_flash, dim3(512, NCH), dim3(256), 0, stream,
                       z_ij, wbt16, gamma, P, kfull, vt, part);
    hipLaunchKernelGGL(k_combine, dim3(512), dim3(256), 0, stream,
                       part, rots, trans, cat);
    hipLaunchKernelGGL(k_out, dim3(3, 64, KSPLIT), dim3(256), 0, stream,
                       cat, Wout, opart);
    hipLaunchKernelGGL(k_outred, dim3(192), dim3(256), 0, stream,
                       opart, bout, out);
}

// Round 10
// 137.559 us; speedup vs baseline: 1.3526x; 1.3526x over previous
//
#include <hip/hip_runtime.h>
#include <hip/hip_bf16.h>
#include <math.h>

#define NRES 512
#define CS   384
#define CZ   128
#define NH   12
#define PW   1152   // packed projection width
#define JB   64     // j per flash block
#define NCH  8      // chunks = NRES/JB
#define PSTRIDE32 1040  // part chunk stride in u32 units
#define KS   6      // k_out K splits (2112 = 6*352)
#define KAW  352    // Kfull row width (11 * 32)

static constexpr float WL_F      = 0.57735026918962576f;   // sqrt(1/3)
static constexpr float HALF_WC_F = 0.11785113019775792f;   // 0.5*sqrt(2/(9*4))

typedef __attribute__((ext_vector_type(8))) short short8v;
typedef __attribute__((ext_vector_type(4))) float floatx4;

__device__ __forceinline__ ushort f2b(float f) {
    union { float f; uint u; } v; v.f = f;
    return (ushort)((v.u + 0x7FFFu + ((v.u >> 16) & 1u)) >> 16);
}
__device__ __forceinline__ float b2f(ushort b) {
    union { uint u; float f; } v; v.u = ((uint)b) << 16; return v.f;
}

// ---------------------------------------------------------------------------
// Kernel 0: pack Wcat[384][1152]; block 0 packs WbT16[16][128] bf16 scaled
// by W_L (rows >= 12 zero).
// ---------------------------------------------------------------------------
__global__ __launch_bounds__(256) void k_pack(
    const float* __restrict__ Wq, const float* __restrict__ Wk,
    const float* __restrict__ Wv, const float* __restrict__ Wqp,
    const float* __restrict__ Wkp, const float* __restrict__ Wvp,
    const float* __restrict__ Wb,
    float* __restrict__ Wcat, ushort* __restrict__ wbt16)
{
    const int c = blockIdx.x;
    for (int col = threadIdx.x; col < PW; col += 256) {
        float v;
        if (col < 192)      v = Wq [(size_t)c * 192 + col];
        else if (col < 384) v = Wk [(size_t)c * 192 + col - 192];
        else if (col < 576) v = Wv [(size_t)c * 192 + col - 384];
        else if (col < 720) v = Wqp[(size_t)c * 144 + col - 576];
        else if (col < 864) v = Wkp[(size_t)c * 144 + col - 720];
        else                v = Wvp[(size_t)c * 288 + col - 864];
        Wcat[(size_t)c * PW + col] = v;
    }
    if (blockIdx.x == 0) {
        for (int idx = threadIdx.x; idx < 16 * 128; idx += 256) {
            const int h = idx >> 7, cc = idx & 127;
            wbt16[idx] = (h < NH) ? f2b(WL_F * Wb[(size_t)cc * NH + h]) : (ushort)0;
        }
    }
}

// ---------------------------------------------------------------------------
// Kernel 0b: WoutT16[384][2112] bf16 = Wout^T. grid (33, 6), LDS transpose.
// ---------------------------------------------------------------------------
__global__ __launch_bounds__(256) void k_wt(
    const float* __restrict__ Wout, ushort* __restrict__ woT)
{
    __shared__ ushort tile[64][72];
    const int k0 = blockIdx.x * 64, c0 = blockIdx.y * 64;
    for (int idx = threadIdx.x; idx < 4096; idx += 256) {
        const int r = idx >> 6, c = idx & 63;
        tile[r][c] = f2b(Wout[(size_t)(k0 + r) * 384 + c0 + c]);
    }
    __syncthreads();
    for (int idx = threadIdx.x; idx < 4096; idx += 256) {
        const int c = idx >> 6, r = idx & 63;
        woT[(size_t)(c0 + c) * 2112 + k0 + r] = tile[r][c];
    }
}

// ---------------------------------------------------------------------------
// Kernel 1: P[512][1152] = s @ Wcat, rigid transform fused for cols >= 576.
// ---------------------------------------------------------------------------
__global__ __launch_bounds__(256) void k_gemm(
    const float* __restrict__ s, const float* __restrict__ Wcat,
    const float* __restrict__ rots, const float* __restrict__ trans,
    float* __restrict__ P)
{
    const int tid = threadIdx.x;
    const int tx = tid & 15, ty = tid >> 4;
    const int n0 = blockIdx.x * 48;
    const int m0 = blockIdx.y * 32;
    __shared__ float As[32][34];
    __shared__ float Bs[32][50];
    __shared__ float rot_lds[32][12];

    if (n0 >= 576) {
        for (int idx = tid; idx < 32 * 12; idx += 256) {
            int r = idx / 12, q = idx % 12;
            rot_lds[r][q] = (q < 9) ? rots[(size_t)(m0 + r) * 9 + q]
                                    : trans[(size_t)(m0 + r) * 3 + q - 9];
        }
    }

    float acc[2][3];
    #pragma unroll
    for (int u = 0; u < 2; ++u)
        #pragma unroll
        for (int v = 0; v < 3; ++v) acc[u][v] = 0.f;

    for (int k0 = 0; k0 < CS; k0 += 32) {
        __syncthreads();
        #pragma unroll
        for (int l = 0; l < 4; ++l) {
            int idx = tid + l * 256;
            int kk = idx & 31, r = idx >> 5;
            As[kk][r] = s[(size_t)(m0 + r) * CS + k0 + kk];
        }
        #pragma unroll
        for (int l = 0; l < 6; ++l) {
            int idx = tid + l * 256;
            int kk = idx / 48, cc = idx % 48;
            Bs[kk][cc] = Wcat[(size_t)(k0 + kk) * PW + n0 + cc];
        }
        __syncthreads();
        #pragma unroll
        for (int kk = 0; kk < 32; ++kk) {
            const float2 a = *(const float2*)&As[kk][ty * 2];
            const float b0 = Bs[kk][tx * 3], b1 = Bs[kk][tx * 3 + 1], b2 = Bs[kk][tx * 3 + 2];
            acc[0][0] += a.x * b0; acc[0][1] += a.x * b1; acc[0][2] += a.x * b2;
            acc[1][0] += a.y * b0; acc[1][1] += a.y * b1; acc[1][2] += a.y * b2;
        }
    }

    #pragma unroll
    for (int u = 0; u < 2; ++u) {
        float v0 = acc[u][0], v1 = acc[u][1], v2 = acc[u][2];
        if (n0 >= 576) {
            const float* RT = rot_lds[ty * 2 + u];
            const float p0 = v0, p1 = v1, p2 = v2;
            v0 = RT[0] * p0 + RT[1] * p1 + RT[2] * p2 + RT[9];
            v1 = RT[3] * p0 + RT[4] * p1 + RT[5] * p2 + RT[10];
            v2 = RT[6] * p0 + RT[7] * p1 + RT[8] * p2 + RT[11];
        }
        float* dst = P + (size_t)(m0 + ty * 2 + u) * PW + n0 + tx * 3;
        dst[0] = v0; dst[1] = v1; dst[2] = v2;
    }
}

// ---------------------------------------------------------------------------
// Kernel 1b: Kfull[512][352] bf16 augmented K rows:
// [0,192) k | [192,336) kg | [336,348) nj_h | 348: 1 | pad
// ---------------------------------------------------------------------------
__global__ __launch_bounds__(128) void k_ka(
    const float* __restrict__ P, ushort* __restrict__ Kfull)
{
    const int j = blockIdx.x;
    const int tid = threadIdx.x;
    __shared__ float njs[NH];
    const float* kr  = P + (size_t)j * PW + 192;
    const float* kgr = P + (size_t)j * PW + 720;
    if (tid < NH) {
        float s = 0.f;
        #pragma unroll
        for (int e = 0; e < 12; ++e) { const float v = kgr[tid * 12 + e]; s += v * v; }
        njs[tid] = s;
    }
    __syncthreads();
    ushort* dst = Kfull + (size_t)j * KAW;
    for (int t = tid; t < KAW; t += 128) {
        float v;
        if (t < 192)       v = kr[t];
        else if (t < 336)  v = kgr[t - 192];
        else if (t < 348)  v = njs[t - 336];
        else if (t == 348) v = 1.0f;
        else               v = 0.f;
        dst[t] = f2b(v);
    }
}

// ---------------------------------------------------------------------------
// Kernel 2: MFMA flash chunk. grid (512 i, 8 jc), 256 threads (4 waves).
// Logits = one fused MFMA chain (15 steps); softmax; o_hat MFMA (4 waves x
// 2 N-tiles from zbT LDS); o/o_hp vector (2 j-halves x 120 cols, LDS reduce).
// part chunk (u32 stride 1040): u16[0,1536) ohat | [1536,1728) o |
// [1728,2016) ohp ; f32 @u32 1008+h = pm, 1020+h = ps.
// ---------------------------------------------------------------------------
__global__ __launch_bounds__(256) void k_flash(
    const float* __restrict__ z, const ushort* __restrict__ wbt16,
    const float* __restrict__ gamma, const float* __restrict__ P,
    const ushort* __restrict__ Kfull, uint* __restrict__ part)
{
    const int i   = blockIdx.x;
    const int jc  = blockIdx.y;
    const int j0  = jc * JB;
    const int tid = threadIdx.x;
    const int wid = tid >> 6, lane = tid & 63;

    __shared__ __align__(16) short zbT[128 * JB];    // 16 KB
    __shared__ __align__(16) short BfT[16 * 488];    // 15.6 KB, B^T [n=16][k=488]
    __shared__ __align__(16) short ltb[16 * 64];     // 2 KB
    __shared__ float ltf[16 * 68];                   // 4.35 KB
    __shared__ float pm[NH], ps[NH];

    uint* pb32   = part + ((size_t)i * NCH + jc) * PSTRIDE32;
    ushort* pb16 = (ushort*)pb32;
    float* pbf   = (float*)pb32;

    // ---- phase 1: zero BfT ----
    for (int idx = tid; idx < 16 * 488 / 2; idx += 256) ((uint*)BfT)[idx] = 0u;
    __syncthreads();

    // ---- phase 2: zbT staging + BfT scatter ----
    {
        const float4* zr = (const float4*)(z + ((size_t)i * NRES + j0 + lane) * CZ + wid * 32);
        float f[32];
        #pragma unroll
        for (int k = 0; k < 8; ++k) {
            const float4 t = zr[k];
            f[k * 4 + 0] = t.x; f[k * 4 + 1] = t.y;
            f[k * 4 + 2] = t.z; f[k * 4 + 3] = t.w;
        }
        #pragma unroll
        for (int m = 0; m < 32; ++m) {
            const int c = wid * 32 + m;
            zbT[c * 64 + (((lane >> 3) ^ (c & 7)) * 8) + (lane & 7)] = (short)f2b(f[m]);
        }
    }
    {
        const float* prow = P + (size_t)i * PW;
        for (int t = tid; t < 360; t += 256) {
            if (t < 192) {
                const int h = t >> 4;
                BfT[h * 488 + t] = (short)f2b(0.25f * WL_F * prow[t]);
            } else if (t < 336) {
                const int e = t - 192, h = e / 12;
                BfT[h * 488 + t] =
                    (short)f2b(2.f * HALF_WC_F * WL_F * gamma[h] * prow[576 + e]);
            } else if (t < 348) {
                const int h = t - 336;
                BfT[h * 488 + t] = (short)f2b(-HALF_WC_F * WL_F * gamma[h]);
            } else {
                const int h = t - 348;
                float s = 0.f;
                #pragma unroll
                for (int e = 0; e < 12; ++e) {
                    const float v = prow[576 + h * 12 + e];
                    s += v * v;
                }
                BfT[h * 488 + 348] = (short)f2b(-HALF_WC_F * WL_F * gamma[h] * s);
            }
        }
        for (int idx = tid; idx < 1024; idx += 256) {
            const int h = idx >> 6, c2 = idx & 63;
            *(uint*)&BfT[h * 488 + 352 + c2 * 2] = ((const uint*)wbt16)[h * 64 + c2];
        }
    }
    __syncthreads();

    // ---- phase 3: fused logits MFMA (15 K-steps) ----
    {
        const int jb = wid * 16 + (lane & 15);
        const int n  = lane & 15;
        const int ko = (lane >> 4) * 8;
        const ushort* arow = Kfull + (size_t)(j0 + jb) * KAW + ko;
        const short*  brow = &BfT[n * 488 + ko];
        const float*  za   = z + ((size_t)i * NRES + j0 + jb) * CZ + ko;
        floatx4 acc = {0.f, 0.f, 0.f, 0.f};
        #pragma unroll
        for (int st = 0; st < 11; ++st) {
            const short8v a = *(const short8v*)(arow + st * 32);
            const short8v b = *(const short8v*)(brow + st * 32);
            acc = __builtin_amdgcn_mfma_f32_16x16x32_bf16(a, b, acc, 0, 0, 0);
        }
        #pragma unroll
        for (int st = 0; st < 4; ++st) {
            const float4 f0 = *(const float4*)(za + st * 32);
            const float4 f1 = *(const float4*)(za + st * 32 + 4);
            short8v a;
            a[0] = (short)f2b(f0.x); a[1] = (short)f2b(f0.y);
            a[2] = (short)f2b(f0.z); a[3] = (short)f2b(f0.w);
            a[4] = (short)f2b(f1.x); a[5] = (short)f2b(f1.y);
            a[6] = (short)f2b(f1.z); a[7] = (short)f2b(f1.w);
            const short8v b = *(const short8v*)(brow + (11 + st) * 32);
            acc = __builtin_amdgcn_mfma_f32_16x16x32_bf16(a, b, acc, 0, 0, 0);
        }
        #pragma unroll
        for (int r = 0; r < 4; ++r)
            ltf[n * 68 + wid * 16 + (lane >> 4) * 4 + r] = acc[r];
    }
    __syncthreads();

    // ---- phase 4: chunk softmax (16 lanes/head) + bf16 prob write ----
    if (tid < 192) {
        const int h = tid >> 4, s = tid & 15;
        float4 v = *(const float4*)&ltf[h * 68 + s * 4];
        float m = fmaxf(fmaxf(v.x, v.y), fmaxf(v.z, v.w));
        #pragma unroll
        for (int o = 1; o < 16; o <<= 1) m = fmaxf(m, __shfl_xor(m, o));
        float4 e;
        e.x = __expf(v.x - m); e.y = __expf(v.y - m);
        e.z = __expf(v.z - m); e.w = __expf(v.w - m);
        float sum = e.x + e.y + e.z + e.w;
        #pragma unroll
        for (int o = 1; o < 16; o <<= 1) sum += __shfl_xor(sum, o);
        *(float4*)&ltf[h * 68 + s * 4] = e;
        const uint lo = (uint)f2b(e.x) | ((uint)f2b(e.y) << 16);
        const uint hi = (uint)f2b(e.z) | ((uint)f2b(e.w) << 16);
        uint* dst = (uint*)&ltb[h * 64 + (((s >> 1) ^ (h & 7)) * 8) + (s & 1) * 4];
        dst[0] = lo; dst[1] = hi;
        if (s == 0) { pm[h] = m; ps[h] = sum; }
    } else {
        const int tt = tid - 192;
        uint* dst = (uint*)&ltb[(12 + (tt >> 4)) * 64 + (tt & 15) * 4];
        dst[0] = 0u; dst[1] = 0u;
    }
    __syncthreads();

    // ---- phase 5a: o_hat MFMA — all 4 waves, 2 N-tiles each ----
    {
        const int hrow = lane & 15;
        const int u0 = (lane >> 4), u1 = u0 + 4;
        const short8v a0 = *(const short8v*)&ltb[hrow * 64 + ((u0 ^ (hrow & 7)) * 8)];
        const short8v a1 = *(const short8v*)&ltb[hrow * 64 + ((u1 ^ (hrow & 7)) * 8)];
        #pragma unroll
        for (int t = 0; t < 2; ++t) {
            const int d = (wid * 2 + t) * 16 + (lane & 15);
            const short8v b0 = *(const short8v*)&zbT[d * 64 + ((u0 ^ (d & 7)) * 8)];
            const short8v b1 = *(const short8v*)&zbT[d * 64 + ((u1 ^ (d & 7)) * 8)];
            floatx4 acc = {0.f, 0.f, 0.f, 0.f};
            acc = __builtin_amdgcn_mfma_f32_16x16x32_bf16(a0, b0, acc, 0, 0, 0);
            acc = __builtin_amdgcn_mfma_f32_16x16x32_bf16(a1, b1, acc, 0, 0, 0);
            #pragma unroll
            for (int r = 0; r < 4; ++r) {
                const int h = u0 * 4 + r;
                if (h < NH) pb16[h * 128 + d] = f2b(acc[r]);
            }
        }
    }

    // ---- phase 5b: o / o_hp — 240 slots = 2 j-halves x 120 cols ----
    {
        float4* halfacc = (float4*)BfT;   // BfT dead after logits phase
        if (tid < 240) {
            const int half = tid / 120, col = tid % 120;
            int h;
            const float* base;
            if (col < 48) { h = col >> 2;               base = P + (size_t)j0 * PW + 384 + col * 4; }
            else          { const int cc = col - 48; h = cc / 6; base = P + (size_t)j0 * PW + 864 + cc * 4; }
            base += (size_t)(half * 32) * PW;
            const float* er = &ltf[h * 68 + half * 32];
            float ax = 0.f, ay = 0.f, az = 0.f, aw = 0.f;
            #pragma unroll 4
            for (int jj = 0; jj < 32; ++jj) {
                const float e = er[jj];
                const float4 v = *(const float4*)(base + (size_t)jj * PW);
                ax += e * v.x; ay += e * v.y; az += e * v.z; aw += e * v.w;
            }
            halfacc[tid] = make_float4(ax, ay, az, aw);
        }
        __syncthreads();
        if (tid < 120) {
            const float4 s0 = halfacc[tid], s1 = halfacc[tid + 120];
            const int off16 = (tid < 48) ? 1536 + tid * 4 : 1728 + (tid - 48) * 4;
            uint* dst = (uint*)&pb16[off16];
            dst[0] = (uint)f2b(s0.x + s1.x) | ((uint)f2b(s0.y + s1.y) << 16);
            dst[1] = (uint)f2b(s0.z + s1.z) | ((uint)f2b(s0.w + s1.w) << 16);
        }
        if (tid < NH) { pbf[1008 + tid] = pm[tid]; pbf[1020 + tid] = ps[tid]; }
    }
}

// ---------------------------------------------------------------------------
// Kernel 3: combine 8 chunks -> cat16 row (bf16). grid 512, 256 threads.
// ---------------------------------------------------------------------------
__global__ __launch_bounds__(256) void k_combine(
    const uint* __restrict__ part, const float* __restrict__ rots,
    const float* __restrict__ trans, ushort* __restrict__ cat16)
{
    const int i   = blockIdx.x;
    const int tid = threadIdx.x;
    __shared__ float wgt[NCH][NH];
    __shared__ float ohp[288];

    const uint* base = part + (size_t)i * NCH * PSTRIDE32;
    if (tid < NH) {
        const int h = tid;
        float mm[NCH];
        float M = -1e30f;
        #pragma unroll
        for (int c = 0; c < NCH; ++c) {
            mm[c] = ((const float*)(base + c * PSTRIDE32))[1008 + h];
            M = fmaxf(M, mm[c]);
        }
        float S = 0.f;
        #pragma unroll
        for (int c = 0; c < NCH; ++c) {
            const float w = __expf(mm[c] - M);
            S += w * ((const float*)(base + c * PSTRIDE32))[1020 + h];
            wgt[c][h] = w;
        }
        const float inv = 1.0f / S;
        #pragma unroll
        for (int c = 0; c < NCH; ++c) wgt[c][h] *= inv;
    }
    __syncthreads();

    ushort* crow = cat16 + (size_t)i * 2112;
    uint*   crowu = (uint*)crow;
    for (int idx2 = tid; idx2 < 768; idx2 += 256) {      // ohat: 1536 bf16
        const int h = idx2 >> 6;
        float v0 = 0.f, v1 = 0.f;
        #pragma unroll
        for (int c = 0; c < NCH; ++c) {
            const uint u = base[c * PSTRIDE32 + idx2];
            const float w = wgt[c][h];
            v0 += b2f((ushort)u) * w;
            v1 += b2f((ushort)(u >> 16)) * w;
        }
        crowu[idx2] = (uint)f2b(v0) | ((uint)f2b(v1) << 16);
    }
    if (tid < 96) {                                       // o: 192 bf16
        const int h = tid >> 3;
        float v0 = 0.f, v1 = 0.f;
        #pragma unroll
        for (int c = 0; c < NCH; ++c) {
            const uint u = base[c * PSTRIDE32 + 768 + tid];
            const float w = wgt[c][h];
            v0 += b2f((ushort)u) * w;
            v1 += b2f((ushort)(u >> 16)) * w;
        }
        crowu[768 + tid] = (uint)f2b(v0) | ((uint)f2b(v1) << 16);
    }
    if (tid < 144) {                                      // ohp: 288 vals
        const int h = tid / 12;
        float v0 = 0.f, v1 = 0.f;
        #pragma unroll
        for (int c = 0; c < NCH; ++c) {
            const uint u = base[c * PSTRIDE32 + 864 + tid];
            const float w = wgt[c][h];
            v0 += b2f((ushort)u) * w;
            v1 += b2f((ushort)(u >> 16)) * w;
        }
        ohp[tid * 2] = v0; ohp[tid * 2 + 1] = v1;
    }
    __syncthreads();

    if (tid < 96) {
        const int h = tid >> 3, p = tid & 7;
        float R[9];
        #pragma unroll
        for (int k = 0; k < 9; ++k) R[k] = rots[(size_t)i * 9 + k];
        const float g0 = ohp[h * 24 + p * 3 + 0] - trans[(size_t)i * 3 + 0];
        const float g1 = ohp[h * 24 + p * 3 + 1] - trans[(size_t)i * 3 + 1];
        const float g2 = ohp[h * 24 + p * 3 + 2] - trans[(size_t)i * 3 + 2];
        const float oy0 = R[0] * g0 + R[3] * g1 + R[6] * g2;
        const float oy1 = R[1] * g0 + R[4] * g1 + R[7] * g2;
        const float oy2 = R[2] * g0 + R[5] * g1 + R[8] * g2;
        crow[1728 + h * 24 + p * 3 + 0] = f2b(oy0);
        crow[1728 + h * 24 + p * 3 + 1] = f2b(oy1);
        crow[1728 + h * 24 + p * 3 + 2] = f2b(oy2);
        crow[2016 + h * 8 + p] = f2b(sqrtf(oy0 * oy0 + oy1 * oy1 + oy2 * oy2));
    }
}

// ---------------------------------------------------------------------------
// Kernel 4: out-proj MFMA. grid (16 m, 12 n, 6 k). 4 waves = 2x2 16x16 tiles.
// A = cat16 rows, B = WoutT16 rows; 11 MFMA of 16x16x32 per wave; no LDS.
// ---------------------------------------------------------------------------
__global__ __launch_bounds__(256) void k_out(
    const ushort* __restrict__ cat16, const ushort* __restrict__ woT,
    float* __restrict__ opart)
{
    const int tid = threadIdx.x;
    const int wid = tid >> 6, lane = tid & 63;
    const int wm = wid >> 1, wn = wid & 1;
    const int i0 = blockIdx.x * 32 + wm * 16;
    const int c0 = blockIdx.y * 32 + wn * 16;
    const int k0 = blockIdx.z * 352;
    const ushort* arow = cat16 + (size_t)(i0 + (lane & 15)) * 2112 + k0 + (lane >> 4) * 8;
    const ushort* brow = woT   + (size_t)(c0 + (lane & 15)) * 2112 + k0 + (lane >> 4) * 8;
    floatx4 acc = {0.f, 0.f, 0.f, 0.f};
    #pragma unroll
    for (int st = 0; st < 11; ++st) {
        const short8v a = *(const short8v*)(arow + st * 32);
        const short8v b = *(const short8v*)(brow + st * 32);
        acc = __builtin_amdgcn_mfma_f32_16x16x32_bf16(a, b, acc, 0, 0, 0);
    }
    float* ob = opart + (size_t)blockIdx.z * 512 * 384;
    #pragma unroll
    for (int r = 0; r < 4; ++r) {
        const int i = i0 + (lane >> 4) * 4 + r;
        ob[(size_t)i * 384 + c0 + (lane & 15)] = acc[r];
    }
}

// Kernel 5: reduce 6 k-partials + bias.
__global__ __launch_bounds__(256) void k_outred(
    const float* __restrict__ opart, const float* __restrict__ bout,
    float* __restrict__ out)
{
    const int e4 = blockIdx.x * 256 + threadIdx.x;
    const float4* p = (const float4*)opart;
    const float4 b = ((const float4*)bout)[e4 % 96];
    float4 r = b;
    #pragma unroll
    for (int k = 0; k < KS; ++k) {
        const float4 v = p[e4 + k * 49152];
        r.x += v.x; r.y += v.y; r.z += v.z; r.w += v.w;
    }
    ((float4*)out)[e4] = r;
}

// ---------------------------------------------------------------------------
extern "C" void kernel_launch(void* const* d_in, const int* in_sizes, int n_in,
                              void* d_out, int out_size, void* d_ws, size_t ws_size,
                              hipStream_t stream)
{
    const float* s_i   = (const float*)d_in[0];
    const float* z_ij  = (const float*)d_in[1];
    const float* rots  = (const float*)d_in[2];
    const float* trans = (const float*)d_in[3];
    const float* Wq    = (const float*)d_in[4];
    const float* Wk    = (const float*)d_in[5];
    const float* Wv    = (const float*)d_in[6];
    const float* Wqp   = (const float*)d_in[7];
    const float* Wkp   = (const float*)d_in[8];
    const float* Wvp   = (const float*)d_in[9];
    const float* Wb    = (const float*)d_in[10];
    const float* gamma = (const float*)d_in[11];
    const float* Wout  = (const float*)d_in[12];
    const float* bout  = (const float*)d_in[13];
    float* ws = (float*)d_ws;
    float*  wcat  = ws;                          // 442368 f
    float*  P     = ws + 442368;                 // 589824 f
    uint*   part  = (uint*)(P + 589824);         // 512*8*1040 u32
    float*  opart = (float*)part;                // aliased (part consumed by
                                                 // k_combine before k_out writes)
    ushort* cat16 = (ushort*)(part + (size_t)512 * NCH * PSTRIDE32);  // 1081344 u16
    ushort* wbt16 = cat16 + 1081344;             // 2048 u16
    ushort* kfull = wbt16 + 2048;                // 512*352 u16
    ushort* woT   = kfull + 512 * KAW;           // 384*2112 u16
    float*  out   = (float*)d_out;

    hipLaunchKernelGGL(k_pack, dim3(384), dim3(256), 0, stream,
                       Wq, Wk, Wv, Wqp, Wkp, Wvp, Wb, wcat, wbt16);
    hipLaunchKernelGGL(k_wt, dim3(33, 6), dim3(256), 0, stream, Wout, woT);
    hipLaunchKernelGGL(k_gemm, dim3(24, 16), dim3(256), 0, stream,
                       s_i, wcat, rots, trans, P);
    hipLaunchKernelGGL(k_ka, dim3(512), dim3(128), 0, stream, P, kfull);
    hipLaunchKernelGGL(k_flash, dim3(512, NCH), dim3(256), 0, stream,
                       z_ij, wbt16, gamma, P, kfull, part);
    hipLaunchKernelGGL(k_combine, dim3(512), dim3(256), 0, stream,
                       part, rots, trans, cat16);
    hipLaunchKernelGGL(k_out, dim3(16, 12, KS), dim3(256), 0, stream,
                       cat16, woT, opart);
    hipLaunchKernelGGL(k_outred, dim3(192), dim3(256), 0, stream,
                       opart, bout, out);
}

// Round 11
// 125.265 us; speedup vs baseline: 1.4853x; 1.0981x over previous
//
#include <hip/hip_runtime.h>
#include <hip/hip_bf16.h>
#include <math.h>

#define NRES 512
#define CS   384
#define CZ   128
#define NH   12
#define PW   1152   // packed projection width
#define JB   64     // j per flash block
#define NCH  8      // chunks = NRES/JB
#define PSTRIDE32 1040  // part chunk stride in u32 units
#define KS   6      // k_out K splits (2112 = 6*352)
#define KAW  352    // Kfull row width (11 * 32)

static constexpr float WL_F      = 0.57735026918962576f;   // sqrt(1/3)
static constexpr float HALF_WC_F = 0.11785113019775792f;   // 0.5*sqrt(2/(9*4))

typedef __attribute__((ext_vector_type(8))) short short8v;
typedef __attribute__((ext_vector_type(4))) float floatx4;

__device__ __forceinline__ ushort f2b(float f) {
    union { float f; uint u; } v; v.f = f;
    return (ushort)((v.u + 0x7FFFu + ((v.u >> 16) & 1u)) >> 16);
}
__device__ __forceinline__ float b2f(ushort b) {
    union { uint u; float f; } v; v.u = ((uint)b) << 16; return v.f;
}

// ---------------------------------------------------------------------------
// Kernel 0: merged prep. blocks [0,384): pack Wcat rows (+wbt16 on block 0);
// blocks [384,582): Wout -> WoutT16 bf16 transpose tiles (33 x 6).
// ---------------------------------------------------------------------------
__global__ __launch_bounds__(256) void k_prep(
    const float* __restrict__ Wq, const float* __restrict__ Wk,
    const float* __restrict__ Wv, const float* __restrict__ Wqp,
    const float* __restrict__ Wkp, const float* __restrict__ Wvp,
    const float* __restrict__ Wb, const float* __restrict__ Wout,
    float* __restrict__ Wcat, ushort* __restrict__ wbt16,
    ushort* __restrict__ woT)
{
    __shared__ ushort tile[64][72];
    const int bx = blockIdx.x;
    if (bx < 384) {
        const int c = bx;
        for (int col = threadIdx.x; col < PW; col += 256) {
            float v;
            if (col < 192)      v = Wq [(size_t)c * 192 + col];
            else if (col < 384) v = Wk [(size_t)c * 192 + col - 192];
            else if (col < 576) v = Wv [(size_t)c * 192 + col - 384];
            else if (col < 720) v = Wqp[(size_t)c * 144 + col - 576];
            else if (col < 864) v = Wkp[(size_t)c * 144 + col - 720];
            else                v = Wvp[(size_t)c * 288 + col - 864];
            Wcat[(size_t)c * PW + col] = v;
        }
        if (bx == 0) {
            for (int idx = threadIdx.x; idx < 16 * 128; idx += 256) {
                const int h = idx >> 7, cc = idx & 127;
                wbt16[idx] = (h < NH) ? f2b(WL_F * Wb[(size_t)cc * NH + h]) : (ushort)0;
            }
        }
    } else {
        const int t = bx - 384;
        const int k0 = (t % 33) * 64, c0 = (t / 33) * 64;
        for (int idx = threadIdx.x; idx < 4096; idx += 256) {
            const int r = idx >> 6, c = idx & 63;
            tile[r][c] = f2b(Wout[(size_t)(k0 + r) * 384 + c0 + c]);
        }
        __syncthreads();
        for (int idx = threadIdx.x; idx < 4096; idx += 256) {
            const int c = idx >> 6, r = idx & 63;
            woT[(size_t)(c0 + c) * 2112 + k0 + r] = tile[r][c];
        }
    }
}

// ---------------------------------------------------------------------------
// Kernel 1: P[512][1152] = s @ Wcat, rigid transform fused for cols >= 576.
// ---------------------------------------------------------------------------
__global__ __launch_bounds__(256) void k_gemm(
    const float* __restrict__ s, const float* __restrict__ Wcat,
    const float* __restrict__ rots, const float* __restrict__ trans,
    float* __restrict__ P)
{
    const int tid = threadIdx.x;
    const int tx = tid & 15, ty = tid >> 4;
    const int n0 = blockIdx.x * 48;
    const int m0 = blockIdx.y * 32;
    __shared__ float As[32][34];
    __shared__ float Bs[32][50];
    __shared__ float rot_lds[32][12];

    if (n0 >= 576) {
        for (int idx = tid; idx < 32 * 12; idx += 256) {
            int r = idx / 12, q = idx % 12;
            rot_lds[r][q] = (q < 9) ? rots[(size_t)(m0 + r) * 9 + q]
                                    : trans[(size_t)(m0 + r) * 3 + q - 9];
        }
    }

    float acc[2][3];
    #pragma unroll
    for (int u = 0; u < 2; ++u)
        #pragma unroll
        for (int v = 0; v < 3; ++v) acc[u][v] = 0.f;

    for (int k0 = 0; k0 < CS; k0 += 32) {
        __syncthreads();
        #pragma unroll
        for (int l = 0; l < 4; ++l) {
            int idx = tid + l * 256;
            int kk = idx & 31, r = idx >> 5;
            As[kk][r] = s[(size_t)(m0 + r) * CS + k0 + kk];
        }
        #pragma unroll
        for (int l = 0; l < 6; ++l) {
            int idx = tid + l * 256;
            int kk = idx / 48, cc = idx % 48;
            Bs[kk][cc] = Wcat[(size_t)(k0 + kk) * PW + n0 + cc];
        }
        __syncthreads();
        #pragma unroll
        for (int kk = 0; kk < 32; ++kk) {
            const float2 a = *(const float2*)&As[kk][ty * 2];
            const float b0 = Bs[kk][tx * 3], b1 = Bs[kk][tx * 3 + 1], b2 = Bs[kk][tx * 3 + 2];
            acc[0][0] += a.x * b0; acc[0][1] += a.x * b1; acc[0][2] += a.x * b2;
            acc[1][0] += a.y * b0; acc[1][1] += a.y * b1; acc[1][2] += a.y * b2;
        }
    }

    #pragma unroll
    for (int u = 0; u < 2; ++u) {
        float v0 = acc[u][0], v1 = acc[u][1], v2 = acc[u][2];
        if (n0 >= 576) {
            const float* RT = rot_lds[ty * 2 + u];
            const float p0 = v0, p1 = v1, p2 = v2;
            v0 = RT[0] * p0 + RT[1] * p1 + RT[2] * p2 + RT[9];
            v1 = RT[3] * p0 + RT[4] * p1 + RT[5] * p2 + RT[10];
            v2 = RT[6] * p0 + RT[7] * p1 + RT[8] * p2 + RT[11];
        }
        float* dst = P + (size_t)(m0 + ty * 2 + u) * PW + n0 + tx * 3;
        dst[0] = v0; dst[1] = v1; dst[2] = v2;
    }
}

// ---------------------------------------------------------------------------
// Kernel 1b: Kfull[512][352] bf16 augmented K rows:
// [0,192) k | [192,336) kg | [336,348) nj_h | 348: 1 | 349-351: 0
// ---------------------------------------------------------------------------
__global__ __launch_bounds__(128) void k_ka(
    const float* __restrict__ P, ushort* __restrict__ Kfull)
{
    const int j = blockIdx.x;
    const int tid = threadIdx.x;
    __shared__ float njs[NH];
    const float* kr  = P + (size_t)j * PW + 192;
    const float* kgr = P + (size_t)j * PW + 720;
    if (tid < NH) {
        float s = 0.f;
        #pragma unroll
        for (int e = 0; e < 12; ++e) { const float v = kgr[tid * 12 + e]; s += v * v; }
        njs[tid] = s;
    }
    __syncthreads();
    ushort* dst = Kfull + (size_t)j * KAW;
    for (int t = tid; t < KAW; t += 128) {
        float v;
        if (t < 192)       v = kr[t];
        else if (t < 336)  v = kgr[t - 192];
        else if (t < 348)  v = njs[t - 336];
        else if (t == 348) v = 1.0f;
        else               v = 0.f;
        dst[t] = f2b(v);
    }
}

// ---------------------------------------------------------------------------
// Kernel 2: MFMA flash chunk. grid (512 i, 8 jc), 256 threads (4 waves).
// LDS 26.2 KB -> 6 blocks/CU. z read ONCE: phase-A thread owns exactly its
// phase-B A-fragment rows/channels (kept in regs) and scatters zbT from them.
// BfT 12x352 built single-pass (each slot final value, no zero pre-pass);
// wbt16 B-fragments read from global (L1-hot). ltf/ltb/halfacc overlay the
// dead BfT region after the logits MFMA.
// part chunk (u32 stride 1040): u16[0,1536) ohat | [1536,1728) o |
// [1728,2016) ohp ; f32 @u32 1008+h = pm, 1020+h = ps.
// ---------------------------------------------------------------------------
__global__ __launch_bounds__(256, 6) void k_flash(
    const float* __restrict__ z, const ushort* __restrict__ wbt16,
    const float* __restrict__ gamma, const float* __restrict__ P,
    const ushort* __restrict__ Kfull, uint* __restrict__ part)
{
    const int i   = blockIdx.x;
    const int jc  = blockIdx.y;
    const int j0  = jc * JB;
    const int tid = threadIdx.x;
    const int wid = tid >> 6, lane = tid & 63;

    __shared__ __align__(16) short zbT[128 * JB];    // 16384 B
    __shared__ __align__(16) char  uni[10240];       // BfT | {ltf, ltb, halfacc}
    __shared__ float pm[NH], ps[NH];

    short*  BfT     = (short*)uni;                   // [12][352] (logits phase)
    float*  ltf     = (float*)uni;                   // [16][68]  (after)
    short*  ltb     = (short*)(uni + 4352);          // [16][64]
    float4* halfacc = (float4*)(uni + 6400);         // [240]

    uint* pb32   = part + ((size_t)i * NCH + jc) * PSTRIDE32;
    ushort* pb16 = (ushort*)pb32;
    float* pbf   = (float*)pb32;

    const int jb = wid * 16 + (lane & 15);           // this thread's j row
    const int ko = (lane >> 4) * 8;                  // channel octet base

    // ---- phase A: z load (once) -> A-frags in regs + zbT scatter; BfT build ----
    short8v af[4];
    {
        const float* za = z + ((size_t)i * NRES + j0 + jb) * CZ + ko;
        #pragma unroll
        for (int m = 0; m < 4; ++m) {
            const float4 f0 = *(const float4*)(za + m * 32);
            const float4 f1 = *(const float4*)(za + m * 32 + 4);
            short8v a;
            a[0] = (short)f2b(f0.x); a[1] = (short)f2b(f0.y);
            a[2] = (short)f2b(f0.z); a[3] = (short)f2b(f0.w);
            a[4] = (short)f2b(f1.x); a[5] = (short)f2b(f1.y);
            a[6] = (short)f2b(f1.z); a[7] = (short)f2b(f1.w);
            af[m] = a;
            #pragma unroll
            for (int e = 0; e < 8; ++e) {
                const int c = ko + m * 32 + e;
                zbT[c * 64 + (((jb >> 3) ^ (c & 7)) * 8) + (jb & 7)] = a[e];
            }
        }
    }
    {
        const float* prow = P + (size_t)i * PW;
        for (int t = tid; t < 12 * 352; t += 256) {
            const int h = t / 352, k = t - h * 352;
            float v = 0.f;
            if (k < 192) {
                if ((k >> 4) == h) v = 0.25f * WL_F * prow[k];
            } else if (k < 336) {
                const int e = k - 192;
                if (e / 12 == h) v = 2.f * HALF_WC_F * WL_F * gamma[h] * prow[576 + e];
            } else if (k < 348) {
                if (k - 336 == h) v = -HALF_WC_F * WL_F * gamma[h];
            } else if (k == 348) {
                float ss = 0.f;
                #pragma unroll
                for (int e = 0; e < 12; ++e) {
                    const float x = prow[576 + h * 12 + e];
                    ss += x * x;
                }
                v = -HALF_WC_F * WL_F * gamma[h] * ss;
            }
            BfT[t] = (short)f2b(v);
        }
    }
    __syncthreads();

    // ---- phase B: fused logits MFMA (15 K-steps) ----
    floatx4 lacc = {0.f, 0.f, 0.f, 0.f};
    {
        const int n  = lane & 15;
        const int nb = (n < NH) ? n : 0;             // clamp garbage rows
        const ushort* arow = Kfull + (size_t)(j0 + jb) * KAW + ko;
        const short*  brow = &BfT[nb * 352 + ko];
        const ushort* wrow = wbt16 + n * 128 + ko;
        #pragma unroll
        for (int st = 0; st < 11; ++st) {
            const short8v a = *(const short8v*)(arow + st * 32);
            const short8v b = *(const short8v*)(brow + st * 32);
            lacc = __builtin_amdgcn_mfma_f32_16x16x32_bf16(a, b, lacc, 0, 0, 0);
        }
        #pragma unroll
        for (int st = 0; st < 4; ++st) {
            const short8v b = *(const short8v*)(wrow + st * 32);
            lacc = __builtin_amdgcn_mfma_f32_16x16x32_bf16(af[st], b, lacc, 0, 0, 0);
        }
    }
    __syncthreads();   // all waves done reading BfT
    {
        const int n = lane & 15;
        #pragma unroll
        for (int r = 0; r < 4; ++r)
            ltf[n * 68 + wid * 16 + (lane >> 4) * 4 + r] = lacc[r];
    }
    __syncthreads();

    // ---- phase C: chunk softmax (16 lanes/head) + bf16 prob write ----
    if (tid < 192) {
        const int h = tid >> 4, s = tid & 15;
        float4 v = *(const float4*)&ltf[h * 68 + s * 4];
        float m = fmaxf(fmaxf(v.x, v.y), fmaxf(v.z, v.w));
        #pragma unroll
        for (int o = 1; o < 16; o <<= 1) m = fmaxf(m, __shfl_xor(m, o));
        float4 e;
        e.x = __expf(v.x - m); e.y = __expf(v.y - m);
        e.z = __expf(v.z - m); e.w = __expf(v.w - m);
        float sum = e.x + e.y + e.z + e.w;
        #pragma unroll
        for (int o = 1; o < 16; o <<= 1) sum += __shfl_xor(sum, o);
        *(float4*)&ltf[h * 68 + s * 4] = e;
        const uint lo = (uint)f2b(e.x) | ((uint)f2b(e.y) << 16);
        const uint hi = (uint)f2b(e.z) | ((uint)f2b(e.w) << 16);
        uint* dst = (uint*)&ltb[h * 64 + (((s >> 1) ^ (h & 7)) * 8) + (s & 1) * 4];
        dst[0] = lo; dst[1] = hi;
        if (s == 0) { pm[h] = m; ps[h] = sum; }
    } else {
        const int tt = tid - 192;
        uint* dst = (uint*)&ltb[(12 + (tt >> 4)) * 64 + (tt & 15) * 4];
        dst[0] = 0u; dst[1] = 0u;
    }
    __syncthreads();

    // ---- phase D: o_hat MFMA — all 4 waves, 2 N-tiles each ----
    {
        const int hrow = lane & 15;
        const int u0 = (lane >> 4), u1 = u0 + 4;
        const short8v a0 = *(const short8v*)&ltb[hrow * 64 + ((u0 ^ (hrow & 7)) * 8)];
        const short8v a1 = *(const short8v*)&ltb[hrow * 64 + ((u1 ^ (hrow & 7)) * 8)];
        #pragma unroll
        for (int t = 0; t < 2; ++t) {
            const int d = (wid * 2 + t) * 16 + (lane & 15);
            const short8v b0 = *(const short8v*)&zbT[d * 64 + ((u0 ^ (d & 7)) * 8)];
            const short8v b1 = *(const short8v*)&zbT[d * 64 + ((u1 ^ (d & 7)) * 8)];
            floatx4 acc = {0.f, 0.f, 0.f, 0.f};
            acc = __builtin_amdgcn_mfma_f32_16x16x32_bf16(a0, b0, acc, 0, 0, 0);
            acc = __builtin_amdgcn_mfma_f32_16x16x32_bf16(a1, b1, acc, 0, 0, 0);
            #pragma unroll
            for (int r = 0; r < 4; ++r) {
                const int h = u0 * 4 + r;
                if (h < NH) pb16[h * 128 + d] = f2b(acc[r]);
            }
        }
    }

    // ---- phase E: o / o_hp — 240 slots = 2 j-halves x 120 cols ----
    {
        if (tid < 240) {
            const int half = tid / 120, col = tid % 120;
            int h;
            const float* base;
            if (col < 48) { h = col >> 2;               base = P + (size_t)j0 * PW + 384 + col * 4; }
            else          { const int cc = col - 48; h = cc / 6; base = P + (size_t)j0 * PW + 864 + cc * 4; }
            base += (size_t)(half * 32) * PW;
            const float* er = &ltf[h * 68 + half * 32];
            float ax = 0.f, ay = 0.f, az = 0.f, aw = 0.f;
            #pragma unroll 4
            for (int jj = 0; jj < 32; ++jj) {
                const float e = er[jj];
                const float4 v = *(const float4*)(base + (size_t)jj * PW);
                ax += e * v.x; ay += e * v.y; az += e * v.z; aw += e * v.w;
            }
            halfacc[tid] = make_float4(ax, ay, az, aw);
        }
        __syncthreads();
        if (tid < 120) {
            const float4 s0 = halfacc[tid], s1 = halfacc[tid + 120];
            const int off16 = (tid < 48) ? 1536 + tid * 4 : 1728 + (tid - 48) * 4;
            uint* dst = (uint*)&pb16[off16];
            dst[0] = (uint)f2b(s0.x + s1.x) | ((uint)f2b(s0.y + s1.y) << 16);
            dst[1] = (uint)f2b(s0.z + s1.z) | ((uint)f2b(s0.w + s1.w) << 16);
        }
        if (tid < NH) { pbf[1008 + tid] = pm[tid]; pbf[1020 + tid] = ps[tid]; }
    }
}

// ---------------------------------------------------------------------------
// Kernel 3: combine 8 chunks -> cat16 row (bf16). grid 512, 256 threads.
// ---------------------------------------------------------------------------
__global__ __launch_bounds__(256) void k_combine(
    const uint* __restrict__ part, const float* __restrict__ rots,
    const float* __restrict__ trans, ushort* __restrict__ cat16)
{
    const int i   = blockIdx.x;
    const int tid = threadIdx.x;
    __shared__ float wgt[NCH][NH];
    __shared__ float ohp[288];

    const uint* base = part + (size_t)i * NCH * PSTRIDE32;
    if (tid < NH) {
        const int h = tid;
        float mm[NCH];
        float M = -1e30f;
        #pragma unroll
        for (int c = 0; c < NCH; ++c) {
            mm[c] = ((const float*)(base + c * PSTRIDE32))[1008 + h];
            M = fmaxf(M, mm[c]);
        }
        float S = 0.f;
        #pragma unroll
        for (int c = 0; c < NCH; ++c) {
            const float w = __expf(mm[c] - M);
            S += w * ((const float*)(base + c * PSTRIDE32))[1020 + h];
            wgt[c][h] = w;
        }
        const float inv = 1.0f / S;
        #pragma unroll
        for (int c = 0; c < NCH; ++c) wgt[c][h] *= inv;
    }
    __syncthreads();

    ushort* crow = cat16 + (size_t)i * 2112;
    uint*   crowu = (uint*)crow;
    for (int idx2 = tid; idx2 < 768; idx2 += 256) {
        const int h = idx2 >> 6;
        float v0 = 0.f, v1 = 0.f;
        #pragma unroll
        for (int c = 0; c < NCH; ++c) {
            const uint u = base[c * PSTRIDE32 + idx2];
            const float w = wgt[c][h];
            v0 += b2f((ushort)u) * w;
            v1 += b2f((ushort)(u >> 16)) * w;
        }
        crowu[idx2] = (uint)f2b(v0) | ((uint)f2b(v1) << 16);
    }
    if (tid < 96) {
        const int h = tid >> 3;
        float v0 = 0.f, v1 = 0.f;
        #pragma unroll
        for (int c = 0; c < NCH; ++c) {
            const uint u = base[c * PSTRIDE32 + 768 + tid];
            const float w = wgt[c][h];
            v0 += b2f((ushort)u) * w;
            v1 += b2f((ushort)(u >> 16)) * w;
        }
        crowu[768 + tid] = (uint)f2b(v0) | ((uint)f2b(v1) << 16);
    }
    if (tid < 144) {
        const int h = tid / 12;
        float v0 = 0.f, v1 = 0.f;
        #pragma unroll
        for (int c = 0; c < NCH; ++c) {
            const uint u = base[c * PSTRIDE32 + 864 + tid];
            const float w = wgt[c][h];
            v0 += b2f((ushort)u) * w;
            v1 += b2f((ushort)(u >> 16)) * w;
        }
        ohp[tid * 2] = v0; ohp[tid * 2 + 1] = v1;
    }
    __syncthreads();

    if (tid < 96) {
        const int h = tid >> 3, p = tid & 7;
        float R[9];
        #pragma unroll
        for (int k = 0; k < 9; ++k) R[k] = rots[(size_t)i * 9 + k];
        const float g0 = ohp[h * 24 + p * 3 + 0] - trans[(size_t)i * 3 + 0];
        const float g1 = ohp[h * 24 + p * 3 + 1] - trans[(size_t)i * 3 + 1];
        const float g2 = ohp[h * 24 + p * 3 + 2] - trans[(size_t)i * 3 + 2];
        const float oy0 = R[0] * g0 + R[3] * g1 + R[6] * g2;
        const float oy1 = R[1] * g0 + R[4] * g1 + R[7] * g2;
        const float oy2 = R[2] * g0 + R[5] * g1 + R[8] * g2;
        crow[1728 + h * 24 + p * 3 + 0] = f2b(oy0);
        crow[1728 + h * 24 + p * 3 + 1] = f2b(oy1);
        crow[1728 + h * 24 + p * 3 + 2] = f2b(oy2);
        crow[2016 + h * 8 + p] = f2b(sqrtf(oy0 * oy0 + oy1 * oy1 + oy2 * oy2));
    }
}

// ---------------------------------------------------------------------------
// Kernel 4: out-proj MFMA. grid (16 m, 12 n, 6 k). 4 waves = 2x2 16x16 tiles.
// ---------------------------------------------------------------------------
__global__ __launch_bounds__(256) void k_out(
    const ushort* __restrict__ cat16, const ushort* __restrict__ woT,
    float* __restrict__ opart)
{
    const int tid = threadIdx.x;
    const int wid = tid >> 6, lane = tid & 63;
    const int wm = wid >> 1, wn = wid & 1;
    const int i0 = blockIdx.x * 32 + wm * 16;
    const int c0 = blockIdx.y * 32 + wn * 16;
    const int k0 = blockIdx.z * 352;
    const ushort* arow = cat16 + (size_t)(i0 + (lane & 15)) * 2112 + k0 + (lane >> 4) * 8;
    const ushort* brow = woT   + (size_t)(c0 + (lane & 15)) * 2112 + k0 + (lane >> 4) * 8;
    floatx4 acc = {0.f, 0.f, 0.f, 0.f};
    #pragma unroll
    for (int st = 0; st < 11; ++st) {
        const short8v a = *(const short8v*)(arow + st * 32);
        const short8v b = *(const short8v*)(brow + st * 32);
        acc = __builtin_amdgcn_mfma_f32_16x16x32_bf16(a, b, acc, 0, 0, 0);
    }
    float* ob = opart + (size_t)blockIdx.z * 512 * 384;
    #pragma unroll
    for (int r = 0; r < 4; ++r) {
        const int i = i0 + (lane >> 4) * 4 + r;
        ob[(size_t)i * 384 + c0 + (lane & 15)] = acc[r];
    }
}

// Kernel 5: reduce 6 k-partials + bias.
__global__ __launch_bounds__(256) void k_outred(
    const float* __restrict__ opart, const float* __restrict__ bout,
    float* __restrict__ out)
{
    const int e4 = blockIdx.x * 256 + threadIdx.x;
    const float4* p = (const float4*)opart;
    const float4 b = ((const float4*)bout)[e4 % 96];
    float4 r = b;
    #pragma unroll
    for (int k = 0; k < KS; ++k) {
        const float4 v = p[e4 + k * 49152];
        r.x += v.x; r.y += v.y; r.z += v.z; r.w += v.w;
    }
    ((float4*)out)[e4] = r;
}

// ---------------------------------------------------------------------------
extern "C" void kernel_launch(void* const* d_in, const int* in_sizes, int n_in,
                              void* d_out, int out_size, void* d_ws, size_t ws_size,
                              hipStream_t stream)
{
    const float* s_i   = (const float*)d_in[0];
    const float* z_ij  = (const float*)d_in[1];
    const float* rots  = (const float*)d_in[2];
    const float* trans = (const float*)d_in[3];
    const float* Wq    = (const float*)d_in[4];
    const float* Wk    = (const float*)d_in[5];
    const float* Wv    = (const float*)d_in[6];
    const float* Wqp   = (const float*)d_in[7];
    const float* Wkp   = (const float*)d_in[8];
    const float* Wvp   = (const float*)d_in[9];
    const float* Wb    = (const float*)d_in[10];
    const float* gamma = (const float*)d_in[11];
    const float* Wout  = (const float*)d_in[12];
    const float* bout  = (const float*)d_in[13];
    float* ws = (float*)d_ws;
    float*  wcat  = ws;                          // 442368 f
    float*  P     = ws + 442368;                 // 589824 f
    uint*   part  = (uint*)(P + 589824);         // 512*8*1040 u32
    float*  opart = (float*)part;                // aliased (sequenced)
    ushort* cat16 = (ushort*)(part + (size_t)512 * NCH * PSTRIDE32);  // 1081344 u16
    ushort* wbt16 = cat16 + 1081344;             // 2048 u16
    ushort* kfull = wbt16 + 2048;                // 512*352 u16
    ushort* woT   = kfull + 512 * KAW;           // 384*2112 u16
    float*  out   = (float*)d_out;

    hipLaunchKernelGGL(k_prep, dim3(582), dim3(256), 0, stream,
                       Wq, Wk, Wv, Wqp, Wkp, Wvp, Wb, Wout, wcat, wbt16, woT);
    hipLaunchKernelGGL(k_gemm, dim3(24, 16), dim3(256), 0, stream,
                       s_i, wcat, rots, trans, P);
    hipLaunchKernelGGL(k_ka, dim3(512), dim3(128), 0, stream, P, kfull);
    hipLaunchKernelGGL(k_flash, dim3(512, NCH), dim3(256), 0, stream,
                       z_ij, wbt16, gamma, P, kfull, part);
    hipLaunchKernelGGL(k_combine, dim3(512), dim3(256), 0, stream,
                       part, rots, trans, cat16);
    hipLaunchKernelGGL(k_out, dim3(16, 12, KS), dim3(256), 0, stream,
                       cat16, woT, opart);
    hipLaunchKernelGGL(k_outred, dim3(192), dim3(256), 0, stream,
                       opart, bout, out);
}